// Round 7
// baseline (71.580 us; speedup 1.0000x reference)
//
#include <hip/hip_runtime.h>
#include <hip/hip_bf16.h>

typedef __attribute__((ext_vector_type(8))) short s16x8;
typedef __attribute__((ext_vector_type(4))) float f32x4;

constexpr int NB = 8, CI = 256, OC = 256, HH = 64, WW = 64, HP = 66, WP = 66;
constexpr int NBASES = 5;
constexpr int WELEMS = OC * CI * 9;      // 589824 per basis
constexpr int BM = 256, BN = 128, BK = 64;
constexpr int AW = 80;                   // padded halo width (66 real + 14 pad)
constexpr int XQ_ELEMS = NB * HP * WP * CI;

static __device__ __forceinline__ unsigned short f2bf(float f) {
    unsigned int u = __builtin_bit_cast(unsigned int, f);
    unsigned int r = (u + 0x7fffu + ((u >> 16) & 1u)) >> 16;   // RNE
    return (unsigned short)r;
}

// ---- 1) per-basis partial sums of |w| : grid 5*64, block 256 ----
__global__ void k_abs_partial(const float* __restrict__ w, float* __restrict__ part) {
    int b = blockIdx.x >> 6, chunk = blockIdx.x & 63;
    const float4* v = (const float4*)(w + (size_t)b * WELEMS + (size_t)chunk * (WELEMS / 64));
    float s = 0.f;
    for (int i = threadIdx.x; i < WELEMS / 64 / 4; i += 256) {
        float4 t = v[i];
        s += fabsf(t.x) + fabsf(t.y) + fabsf(t.z) + fabsf(t.w);
    }
    #pragma unroll
    for (int off = 32; off; off >>= 1) s += __shfl_down(s, off, 64);
    __shared__ float ls[4];
    int lane = threadIdx.x & 63, wid = threadIdx.x >> 6;
    if (lane == 0) ls[wid] = s;
    __syncthreads();
    if (threadIdx.x == 0) part[blockIdx.x] = ls[0] + ls[1] + ls[2] + ls[3];
}

// ---- 2) fused prep: blocks [0,256) build wsum; blocks [256,768) quantize x ----
__global__ void k_prep(const float* __restrict__ w, const float* __restrict__ part,
                       unsigned short* __restrict__ wsum,
                       const float* __restrict__ x, unsigned short* __restrict__ xq) {
    __shared__ float sLDS[NBASES];             // wsum branch only
    int tid = threadIdx.x;

    if (blockIdx.x < OC) {
        // ---- wsum[tap][o][i] = (1/5) * sum_b sign(w[b,o,i,tap])*s_b ----
        if (tid < 64) {
            #pragma unroll
            for (int b = 0; b < NBASES; ++b) {
                float v = part[b * 64 + tid];
                #pragma unroll
                for (int off = 32; off; off >>= 1) v += __shfl_down(v, off, 64);
                if (tid == 0) sLDS[b] = v * (1.0f / (float)WELEMS);
            }
        }
        __syncthreads();
        float sc[NBASES];
        #pragma unroll
        for (int b = 0; b < NBASES; ++b) sc[b] = sLDS[b];

        int o = blockIdx.x, i = tid;
        const float* base = w + ((size_t)(o * CI + i)) * 9;
        float acc[9];
        #pragma unroll
        for (int t = 0; t < 9; ++t) acc[t] = 0.f;
        #pragma unroll
        for (int b = 0; b < NBASES; ++b) {
            const float* wb = base + (size_t)b * WELEMS;
            #pragma unroll
            for (int t = 0; t < 9; ++t) {
                float xv = wb[t];
                acc[t] += (xv > 0.f) ? sc[b] : ((xv < 0.f) ? -sc[b] : 0.f);
            }
        }
        #pragma unroll
        for (int t = 0; t < 9; ++t)
            wsum[(t * OC + o) * CI + i] = f2bf(acc[t] * 0.2f);
        return;
    }

    // ---- xq_pad quantize: no LDS. thread gathers 8 channels for one w ----
    int nh = blockIdx.x - OC, n = nh >> 6, h = nh & 63;
    const float* xb = x + ((size_t)n * CI) * (HH * WW) + h * WW;   // + c*4096 + w
    unsigned short* ob = xq + ((size_t)(n * HP + (h + 1)) * WP + 1) * CI;
    int w4 = tid >> 2;             // 0..63
    int cl = tid & 3;              // 0..3
    #pragma unroll
    for (int p = 0; p < 8; ++p) {
        int c = (p * 4 + cl) * 8;  // 8-channel group
        unsigned short pk[8];
        #pragma unroll
        for (int i = 0; i < 8; ++i) {
            float v = xb[(size_t)(c + i) * (HH * WW) + w4];
            v = rintf(fminf(fmaxf(v, 0.f), 1.f));
            pk[i] = f2bf(v);
        }
        *(s16x8*)(ob + w4 * CI + c) = *(const s16x8*)pk;
    }
    // side border cells of this padded row (w_p = 0 and 65)
    (ob - CI)[tid] = 0;
    (ob + 64 * CI)[tid] = 0;
    if (h == 0) {
        unsigned short* r0 = xq + ((size_t)(n * HP + 0) * WP) * CI;
        for (int i = tid; i < WP * CI / 8; i += 256) {
            s16x8 z = {};
            *(s16x8*)(r0 + i * 8) = z;
        }
    }
    if (h == HH - 1) {
        unsigned short* r65 = xq + ((size_t)(n * HP + (HP - 1)) * WP) * CI;
        for (int i = tid; i < WP * CI / 8; i += 256) {
            s16x8 z = {};
            *(s16x8*)(r65 + i * 8) = z;
        }
    }
}

// ---- 3) conv: kw-halo A-reuse. A staged once per (kh, c0), all 3 kw taps
//      read shifted windows from LDS. A ring x2 (40KB), B ring x4 (16KB).
//      R5's proven 2-barrier/step compute shape; counted vmcnt 4/9 steady. ----
__launch_bounds__(512, 1)
__global__ void k_conv(const unsigned short* __restrict__ xq,
                       const unsigned short* __restrict__ wsum,
                       float* __restrict__ out) {
    __shared__ __align__(16) unsigned short lA[2][4 * AW * 64];  // 2 x 40 KB
    __shared__ __align__(16) unsigned short lB[4][BN * 64];      // 4 x 16 KB

    // XCD-chunked swizzle: 256 blocks, 32 logical tiles per XCD
    int bid = blockIdx.x;
    int bx = ((bid & 7) << 5) | (bid >> 3);
    int pt = bx >> 1, ot = bx & 1;
    int pb = pt * BM;                  // first pixel (n*4096 + h*64 + w)
    int n = pb >> 12;
    int h0 = (pb >> 6) & 63;           // h-rows h0..h0+3; halo rows h0..h0+5 (padded)
    int oc0 = ot * BN;
    int tid = threadIdx.x;

    // ---- staging precompute ----
    // A: tile [4 rows][AW wpos][64 ch]; chunk cidx=(r*AW+wpos)*8+sp, 5/thread
    int aDst[5], aSrcO[5];
    #pragma unroll
    for (int k = 0; k < 5; ++k) {
        int cidx = tid + k * 512;
        int r = cidx / 640;
        int rem = cidx - r * 640;
        int wpos = rem >> 3, sp = rem & 7;
        aDst[k] = cidx * 8;
        aSrcO[k] = r * (WP * CI) + wpos * CI + ((sp ^ (wpos & 7)) * 8);
    }
    // B: tile [128 oc][64 ch]; chunk c=row*8+sp, 2/thread
    int bDst[2], bSrcO[2];
    #pragma unroll
    for (int k = 0; k < 2; ++k) {
        int c = tid + k * 512;
        int row = c >> 3, sp = c & 7;
        bDst[k] = c * 8;
        bSrcO[k] = row * CI + ((sp ^ (row & 7)) * 8);
    }

    int lane = tid & 63, wid = tid >> 6;
    int wm = wid >> 1, wn = wid & 1;        // 4M x 2N waves, 64x64 per wave
    int g = lane >> 4, r16 = lane & 15;

    // A frag base per (kw, half): +mq*16*64 per m-quarter
    int aBase[3][2];
    #pragma unroll
    for (int kw = 0; kw < 3; ++kw) {
        int swz = (r16 + kw) & 7;
        #pragma unroll
        for (int hf = 0; hf < 2; ++hf)
            aBase[kw][hf] = (wm * AW + r16 + kw) * 64 + (((hf * 4 + g) ^ swz) * 8);
    }
    int fB[4][2];
    #pragma unroll
    for (int nq = 0; nq < 4; ++nq) {
        int row = wn * 64 + nq * 16 + r16;
        #pragma unroll
        for (int hf = 0; hf < 2; ++hf)
            fB[nq][hf] = row * 64 + (((hf * 4 + g) ^ (r16 & 7)) * 8);
    }

    int aGlobBase = (n * HP + h0) * WP * CI;   // + kh*WP*CI + c0
    int bGlobBase = oc0 * CI;                  // + tap*OC*CI + c0

    f32x4 acc[4][4] = {};

    auto stageA = [&](int ai) {                // ai = group 0..11: (kh, c0)
        int buf = ai & 1;
        int kh = ai >> 2, c0 = (ai & 3) << 6;
        int base = aGlobBase + kh * (WP * CI) + c0;
        #pragma unroll
        for (int k = 0; k < 5; ++k) {
            int src = base + aSrcO[k];
            src = src < (XQ_ELEMS - 8) ? src : (XQ_ELEMS - 8);   // pad-overrun clamp
            __builtin_amdgcn_global_load_lds(
                (const __attribute__((address_space(1))) void*)(xq + src),
                (__attribute__((address_space(3))) void*)(&lA[buf][aDst[k]]), 16, 0, 0);
        }
    };
    auto stageB = [&](int jj) {                // jj = K-step 0..35: (tap, c0)
        int buf = jj & 3;
        int q = jj / 3;
        int kw = jj - q * 3;
        int kh = q >> 2, c0 = (q & 3) << 6;
        int tap = kh * 3 + kw;
        const unsigned short* src = wsum + tap * (OC * CI) + bGlobBase + c0;
        #pragma unroll
        for (int k = 0; k < 2; ++k)
            __builtin_amdgcn_global_load_lds(
                (const __attribute__((address_space(1))) void*)(src + bSrcO[k]),
                (__attribute__((address_space(3))) void*)(&lB[buf][bDst[k]]), 16, 0, 0);
    };

    // prologue: A(0) + B(0..2) in flight (11 loads/thread)
    stageA(0); stageB(0); stageB(1); stageB(2);

    #pragma unroll 1
    for (int a = 0; a < 12; ++a) {
        const unsigned short* A = &lA[a & 1][0];
        #pragma unroll
        for (int kw = 0; kw < 3; ++kw) {
            int j = a * 3 + kw;
            // counted waits (derived + simulated): steady kw0->4, else 9; tail 4/2/0
            if (a < 11) {
                if (kw == 0) asm volatile("s_waitcnt vmcnt(4)" ::: "memory");
                else         asm volatile("s_waitcnt vmcnt(9)" ::: "memory");
            } else {
                if (kw == 0)      asm volatile("s_waitcnt vmcnt(4)" ::: "memory");
                else if (kw == 1) asm volatile("s_waitcnt vmcnt(2)" ::: "memory");
                else              asm volatile("s_waitcnt vmcnt(0)" ::: "memory");
            }
            __builtin_amdgcn_s_barrier();      // A[a], B[j] ready; prev step's readers done
            if (kw == 0 && a < 11) stageA(a + 1);   // into other A buf (safe post-barrier)
            if (j + 3 < 36) stageB(j + 3);          // into lB[(j-1)&3] (safe post-barrier)
            const unsigned short* B = &lB[j & 3][0];

            // ---- half 0: 8 ds_read + 16 MFMA ----
            {
                s16x8 aR[4], bR[4];
                #pragma unroll
                for (int mq = 0; mq < 4; ++mq)
                    aR[mq] = *(const s16x8*)(A + aBase[kw][0] + mq * (16 * 64));
                #pragma unroll
                for (int nq = 0; nq < 4; ++nq)
                    bR[nq] = *(const s16x8*)(B + fB[nq][0]);
                asm volatile("s_waitcnt lgkmcnt(0)" ::: "memory");
                __builtin_amdgcn_s_setprio(1);
                #pragma unroll
                for (int mq = 0; mq < 4; ++mq)
                    #pragma unroll
                    for (int nq = 0; nq < 4; ++nq)
                        acc[mq][nq] = __builtin_amdgcn_mfma_f32_16x16x32_bf16(
                            aR[mq], bR[nq], acc[mq][nq], 0, 0, 0);
                __builtin_amdgcn_s_setprio(0);
            }
            asm volatile("s_barrier" ::: "memory");

            // ---- half 1: 8 ds_read + 16 MFMA ----
            {
                s16x8 aR[4], bR[4];
                #pragma unroll
                for (int mq = 0; mq < 4; ++mq)
                    aR[mq] = *(const s16x8*)(A + aBase[kw][1] + mq * (16 * 64));
                #pragma unroll
                for (int nq = 0; nq < 4; ++nq)
                    bR[nq] = *(const s16x8*)(B + fB[nq][1]);
                asm volatile("s_waitcnt lgkmcnt(0)" ::: "memory");
                __builtin_amdgcn_s_setprio(1);
                #pragma unroll
                for (int mq = 0; mq < 4; ++mq)
                    #pragma unroll
                    for (int nq = 0; nq < 4; ++nq)
                        acc[mq][nq] = __builtin_amdgcn_mfma_f32_16x16x32_bf16(
                            aR[mq], bR[nq], acc[mq][nq], 0, 0, 0);
                __builtin_amdgcn_s_setprio(0);
            }
            // next step leads with vmcnt + barrier
        }
    }

    // epilogue: C/D 16x16: col=lane&15 (oc), row=(lane>>4)*4+reg (pixel)
    int hw0 = pb & 4095;
    #pragma unroll
    for (int mq = 0; mq < 4; ++mq) {
        int pl = wm * 64 + mq * 16 + g * 4;
        #pragma unroll
        for (int nq = 0; nq < 4; ++nq) {
            int oc = oc0 + wn * 64 + nq * 16 + r16;
            float4 v;
            v.x = acc[mq][nq][0]; v.y = acc[mq][nq][1];
            v.z = acc[mq][nq][2]; v.w = acc[mq][nq][3];
            *(float4*)(out + ((size_t)(n * OC + oc) << 12) + hw0 + pl) = v;
        }
    }
}

extern "C" void kernel_launch(void* const* d_in, const int* in_sizes, int n_in,
                              void* d_out, int out_size, void* d_ws, size_t ws_size,
                              hipStream_t stream) {
    (void)in_sizes; (void)n_in; (void)out_size; (void)ws_size;
    const float* x   = (const float*)d_in[0];
    const float* wts = (const float*)d_in[1];
    float* out = (float*)d_out;
    char* wsb = (char*)d_ws;
    float* part            = (float*)wsb;                 // 320 floats
    unsigned short* wsum   = (unsigned short*)(wsb + 4096);          // 9*256*256 bf16 = 1.125 MiB
    unsigned short* xq     = (unsigned short*)(wsb + (size_t)(2u << 20)); // 8*66*66*256 bf16 ~ 17 MiB

    hipLaunchKernelGGL(k_abs_partial, dim3(NBASES * 64), dim3(256), 0, stream, wts, part);
    hipLaunchKernelGGL(k_prep, dim3(OC + NB * HH), dim3(256), 0, stream,
                       wts, part, wsum, x, xq);
    hipLaunchKernelGGL(k_conv, dim3((NB * HH * WW / BM) * (OC / BN)), dim3(512), 0, stream,
                       xq, wsum, out);
}

// Round 8
// 53.683 us; speedup vs baseline: 1.3334x; 1.3334x over previous
//
#include <hip/hip_runtime.h>
#include <hip/hip_bf16.h>

typedef __attribute__((ext_vector_type(4))) int i32x4;

constexpr int NB = 8, CI = 256, OC = 256, HH = 64, WW = 64, HP = 66, WP = 66;
constexpr int NBASES = 5;
constexpr int WELEMS = OC * CI * 9;      // 589824 per basis
constexpr int NT = 36;                   // 9 taps x 4 chunks of 64 channels

// ---- 1) per-basis partial sums of |w| : grid 5*64, block 256 ----
__global__ void k_abs_partial(const float* __restrict__ w, float* __restrict__ part) {
    int b = blockIdx.x >> 6, chunk = blockIdx.x & 63;
    const float4* v = (const float4*)(w + (size_t)b * WELEMS + (size_t)chunk * (WELEMS / 64));
    float s = 0.f;
    for (int i = threadIdx.x; i < WELEMS / 64 / 4; i += 256) {
        float4 t = v[i];
        s += fabsf(t.x) + fabsf(t.y) + fabsf(t.z) + fabsf(t.w);
    }
    #pragma unroll
    for (int off = 32; off; off >>= 1) s += __shfl_down(s, off, 64);
    __shared__ float ls[4];
    int lane = threadIdx.x & 63, wid = threadIdx.x >> 6;
    if (lane == 0) ls[wid] = s;
    __syncthreads();
    if (threadIdx.x == 0) part[blockIdx.x] = ls[0] + ls[1] + ls[2] + ls[3];
}

// ---- 2) fused prep (i8): blocks [0,256) build wsum8+scale; [256,768) quantize x ----
__global__ void k_prep(const float* __restrict__ w, const float* __restrict__ part,
                       signed char* __restrict__ wsum8, float* __restrict__ scl,
                       const float* __restrict__ x, signed char* __restrict__ xq) {
    __shared__ float sLDS[NBASES];
    int tid = threadIdx.x;

    if (blockIdx.x < OC) {
        if (tid < 64) {
            #pragma unroll
            for (int b = 0; b < NBASES; ++b) {
                float v = part[b * 64 + tid];
                #pragma unroll
                for (int off = 32; off; off >>= 1) v += __shfl_down(v, off, 64);
                if (tid == 0) sLDS[b] = v * (1.0f / (float)WELEMS);
            }
        }
        __syncthreads();
        float sc[NBASES];
        #pragma unroll
        for (int b = 0; b < NBASES; ++b) sc[b] = sLDS[b];
        float sSum = sc[0] + sc[1] + sc[2] + sc[3] + sc[4];
        float invS = 127.0f / sSum;                 // wq = rint(acc * 127 / sSum)
        if (blockIdx.x == 0 && tid == 0)
            scl[0] = sSum * (0.2f / 127.0f);        // out scale = alpha/127, alpha=sSum/5

        int o = blockIdx.x, i = tid;
        const float* base = w + ((size_t)(o * CI + i)) * 9;
        float acc[9];
        #pragma unroll
        for (int t = 0; t < 9; ++t) acc[t] = 0.f;
        #pragma unroll
        for (int b = 0; b < NBASES; ++b) {
            const float* wb = base + (size_t)b * WELEMS;
            #pragma unroll
            for (int t = 0; t < 9; ++t) {
                float xv = wb[t];
                acc[t] += (xv > 0.f) ? sc[b] : ((xv < 0.f) ? -sc[b] : 0.f);
            }
        }
        #pragma unroll
        for (int t = 0; t < 9; ++t)
            wsum8[(t * OC + o) * CI + i] = (signed char)__float2int_rn(acc[t] * invS);
        return;
    }

    // ---- xq_pad[n][h+1][w+1][c] = i8(round(clip(x,0,1))), borders 0 ----
    int nh = blockIdx.x - OC, n = nh >> 6, h = nh & 63;
    const float* xb = x + ((size_t)n * CI) * (HH * WW) + h * WW;   // + c*4096 + w
    signed char* ob = xq + ((size_t)(n * HP + (h + 1)) * WP + 1) * CI;
    int w4 = tid >> 2;             // 0..63
    int cl = tid & 3;              // 0..3
    #pragma unroll
    for (int p = 0; p < 4; ++p) {
        int c = (p * 4 + cl) * 16;
        signed char pk[16];
        #pragma unroll
        for (int i = 0; i < 16; ++i) {
            float v = xb[(size_t)(c + i) * (HH * WW) + w4];
            pk[i] = (signed char)rintf(fminf(fmaxf(v, 0.f), 1.f));
        }
        *(int4*)(ob + w4 * CI + c) = *(const int4*)pk;
    }
    (ob - CI)[tid] = 0;
    (ob + 64 * CI)[tid] = 0;
    if (h == 0) {
        signed char* r0 = xq + ((size_t)(n * HP + 0) * WP) * CI;
        int4 z = {0, 0, 0, 0};
        for (int i = tid; i < WP * CI / 16; i += 256) *(int4*)(r0 + i * 16) = z;
    }
    if (h == HH - 1) {
        signed char* r65 = xq + ((size_t)(n * HP + (HP - 1)) * WP) * CI;
        int4 z = {0, 0, 0, 0};
        for (int i = tid; i < WP * CI / 16; i += 256) *(int4*)(r65 + i * 16) = z;
    }
}

// ---- 3) conv i8: 128x128 tile, K-chunk 64 bytes, 4 waves, 3-buf LDS (48KB),
//      2 blocks/CU, R5's proven single-phase pipelined step, mfma_i32_16x16x64_i8 ----
__launch_bounds__(256, 2)
__global__ void k_conv(const signed char* __restrict__ xq,
                       const signed char* __restrict__ wsum,
                       const float* __restrict__ scl,
                       float* __restrict__ out) {
    __shared__ __align__(16) signed char lA[3][128 * 64];  // 3 x 8 KB
    __shared__ __align__(16) signed char lB[3][128 * 64];  // 3 x 8 KB

    float so = scl[0];

    // XCD-chunked swizzle: 512 blocks, 64 logical per XCD (= 1 image x both oc halves)
    int bid = blockIdx.x;
    int bx = ((bid & 7) << 6) | (bid >> 3);
    int pt = bx >> 1, ot = bx & 1;
    int pb = pt * 128;                 // first pixel (n*4096 + h*64 + w); 2 h-rows
    int n = pb >> 12;
    int h0 = (pb >> 6) & 63;
    int oc0 = ot * 128;
    int tid = threadIdx.x;

    int base0 = (n * HP + h0) * WP * CI;   // byte offset (CI bytes per pixel)
    int bBase0 = oc0 * CI;

    // staging: 512 chunks of 16B per tile; chunk c: row=c>>2, sp=c&3,
    // fetch logical k-slot l = sp ^ ((row>>1)&3)  (linear LDS dest, swizzled source)
    int aOff[2], bOff[2];
    #pragma unroll
    for (int k = 0; k < 2; ++k) {
        int c = tid + k * 256;
        int row = c >> 2, sp = c & 3;
        int l = sp ^ ((row >> 1) & 3);
        aOff[k] = ((row >> 6) * WP + (row & 63)) * CI + l * 16;
        bOff[k] = row * CI + l * 16;
    }

    int lane = tid & 63, wid = tid >> 6;
    int wm = wid >> 1, wn = wid & 1;        // 2M x 2N waves, 64x64 per wave
    int g = lane >> 4, r16 = lane & 15;
    // frag byte offsets: row r, logical slot g lives at physical g ^ ((r>>1)&3)
    int fA[4], fB[4];
    #pragma unroll
    for (int q = 0; q < 4; ++q) {
        int ra = wm * 64 + q * 16 + r16;
        fA[q] = ra * 64 + (g ^ ((ra >> 1) & 3)) * 16;
        int rb = wn * 64 + q * 16 + r16;
        fB[q] = rb * 64 + (g ^ ((rb >> 1) & 3)) * 16;
    }

    i32x4 acc[4][4] = {};

    auto stage = [&](int t) {
        int buf = t % 3;
        int tap = t >> 2;
        int c0 = (t & 3) << 6;             // 64-byte channel chunk
        int kh = (tap * 171) >> 9;         // tap/3
        int kw = tap - kh * 3;
        const signed char* aSrc = xq + base0 + (kh * WP + kw) * CI + c0;
        const signed char* bSrc = wsum + tap * (OC * CI) + bBase0 + c0;
        #pragma unroll
        for (int k = 0; k < 2; ++k) {
            __builtin_amdgcn_global_load_lds(
                (const __attribute__((address_space(1))) void*)(aSrc + aOff[k]),
                (__attribute__((address_space(3))) void*)(&lA[buf][(tid + k * 256) * 16]), 16, 0, 0);
            __builtin_amdgcn_global_load_lds(
                (const __attribute__((address_space(1))) void*)(bSrc + bOff[k]),
                (__attribute__((address_space(3))) void*)(&lB[buf][(tid + k * 256) * 16]), 16, 0, 0);
        }
    };

    // prologue: 2 K-steps in flight (8 loads/thread)
    stage(0); stage(1);

    #pragma unroll 1
    for (int t = 0; t < NT; ++t) {
        int buf = t % 3;
        // counted wait: my 4 loads for step t are the oldest; t+1's 4 stay in flight
        if (t < NT - 1) asm volatile("s_waitcnt vmcnt(4)" ::: "memory");
        else            asm volatile("s_waitcnt vmcnt(0)" ::: "memory");
        __builtin_amdgcn_s_barrier();      // buf[t%3] ready; prev step's readers done
        if (t + 2 < NT) stage(t + 2);      // writes buf[(t-1)%3], free after barrier

        i32x4 aR[4], bR[4];
        #pragma unroll
        for (int q = 0; q < 4; ++q) aR[q] = *(const i32x4*)&lA[buf][fA[q]];
        #pragma unroll
        for (int q = 0; q < 4; ++q) bR[q] = *(const i32x4*)&lB[buf][fB[q]];
        asm volatile("s_waitcnt lgkmcnt(0)" ::: "memory");
        __builtin_amdgcn_sched_barrier(0);
        __builtin_amdgcn_s_setprio(1);
        #pragma unroll
        for (int mq = 0; mq < 4; ++mq)
            #pragma unroll
            for (int nq = 0; nq < 4; ++nq)
                acc[mq][nq] = __builtin_amdgcn_mfma_i32_16x16x64_i8(
                    aR[mq], bR[nq], acc[mq][nq], 0, 0, 0);
        __builtin_amdgcn_s_setprio(0);
    }

    // epilogue: C/D 16x16: col=lane&15 (oc), row=(lane>>4)*4+reg (pixel); scale to fp32
    int hw0 = pb & 4095;
    #pragma unroll
    for (int mq = 0; mq < 4; ++mq) {
        int pl = wm * 64 + mq * 16 + g * 4;
        #pragma unroll
        for (int nq = 0; nq < 4; ++nq) {
            int oc = oc0 + wn * 64 + nq * 16 + r16;
            float4 v;
            v.x = (float)acc[mq][nq][0] * so;
            v.y = (float)acc[mq][nq][1] * so;
            v.z = (float)acc[mq][nq][2] * so;
            v.w = (float)acc[mq][nq][3] * so;
            *(float4*)(out + ((size_t)(n * OC + oc) << 12) + hw0 + pl) = v;
        }
    }
}

extern "C" void kernel_launch(void* const* d_in, const int* in_sizes, int n_in,
                              void* d_out, int out_size, void* d_ws, size_t ws_size,
                              hipStream_t stream) {
    (void)in_sizes; (void)n_in; (void)out_size; (void)ws_size;
    const float* x   = (const float*)d_in[0];
    const float* wts = (const float*)d_in[1];
    float* out = (float*)d_out;
    char* wsb = (char*)d_ws;
    float* part          = (float*)wsb;                        // 320 floats
    float* scl           = (float*)(wsb + 2048);               // 1 float
    signed char* wsum8   = (signed char*)(wsb + 4096);         // 9*256*256 = 576 KB
    signed char* xq8     = (signed char*)(wsb + (size_t)(2u << 20)); // 8*66*66*256 ~ 8.9 MB

    hipLaunchKernelGGL(k_abs_partial, dim3(NBASES * 64), dim3(256), 0, stream, wts, part);
    hipLaunchKernelGGL(k_prep, dim3(OC + NB * HH), dim3(256), 0, stream,
                       wts, part, wsum8, scl, x, xq8);
    hipLaunchKernelGGL(k_conv, dim3((NB * HH * WW / 128) * (OC / 128)), dim3(256), 0, stream,
                       xq8, wsum8, scl, out);
}